// Round 5
// baseline (192.601 us; speedup 1.0000x reference)
//
#include <hip/hip_runtime.h>
#include <hip/hip_bf16.h>
#include <stdint.h>

// Problem constants (B=8, S=2048, E=1024, H=128, DK=8)
#define M_DIM 16384   // B*S
#define N_DIM 1024    // E (output features)
#define K_DIM 1024    // E (reduction)

typedef __attribute__((ext_vector_type(8))) short short8;
typedef __attribute__((ext_vector_type(4))) float f32x4;

// async global->LDS, 16B per lane. LDS dest must be wave-uniform base + lane*16.
#define GLD_LDS(g, l) __builtin_amdgcn_global_load_lds( \
    (const __attribute__((address_space(1))) unsigned int*)(g), \
    (__attribute__((address_space(3))) unsigned int*)(l), 16, 0, 0)

__device__ __forceinline__ unsigned short f2bf(float f) {
  union { float f; unsigned int u; } v;
  v.f = f;
  unsigned int u = v.u + 0x7FFFu + ((v.u >> 16) & 1u);  // RNE
  return (unsigned short)(u >> 16);
}

// W_bf16[n,k] = bf16(W[n,k]). Lane-contiguous: block owns 2048 contiguous elems.
#define PREP_W_BLOCKS (N_DIM * K_DIM / 2048)   // 512
__global__ __launch_bounds__(256) void prep_w(const float* __restrict__ W,
                                              unsigned short* __restrict__ Wb) {
  const int tid = threadIdx.x;
  const long base = (long)blockIdx.x * 2048;
#pragma unroll
  for (int p = 0; p < 2; ++p) {
    const long i = base + p * 1024 + tid * 4;
    const float4 wv = *(const float4*)(W + i);
    ushort4 o;
    o.x = f2bf(wv.x);
    o.y = f2bf(wv.y);
    o.z = f2bf(wv.z);
    o.w = f2bf(wv.w);
    *(ushort4*)(Wb + i) = o;
  }
}

// Fused: C[m,n] = sum_k cos(x[m,k]+theta[k]) * W[n,k] + bias[n].
// A is NEVER materialized in HBM (r4 post-mortem: prep_a ~20us + 67 MB round
// trip deleted). A-tile staging: thread loads x fp32 (2x float4/chunk), adds
// theta, __cosf, RNE-packs to bf16, ds_write_b128 into the SAME swizzled LDS
// layout the DMA path used. B-tile keeps async global_load_lds from pre-cast Wb.
// 128x128 tile, BK=64, 4 waves of 64x64, 16x16x32 bf16 MFMA (reverted from
// 32x32: 4-way structural LDS conflict, r4), XOR chunk swizzle (conflicts=0),
// XCD-banded block remap (FETCH once per band, r3).
__global__ __launch_bounds__(256) void gemm_fused(const float* __restrict__ x,
                                                  const float* __restrict__ theta,
                                                  const unsigned short* __restrict__ Bt,
                                                  const float* __restrict__ bias,
                                                  float* __restrict__ C) {
  constexpr int BM = 128, BN = 128, BK = 64;
  __shared__ unsigned short As[BM * BK];  // 16 KB
  __shared__ unsigned short Bs[BN * BK];  // 16 KB
  const int tid = threadIdx.x;

  const int L = blockIdx.y * 8 + blockIdx.x;  // linear dispatch id
  const int bx = (L >> 3) & 7;                // N-tile 0..7
  const int by = (L & 7) * 16 + (L >> 6);     // M-tile 0..127, banded per XCD
  const int m0 = by * BM;
  const int n0 = bx * BN;

  const int lane = tid & 63;
  const int wave = tid >> 6;
  const int wm = (wave >> 1) * 64;  // wave tile origin in M
  const int wn = (wave & 1) * 64;   // wave tile origin in N

  f32x4 acc[4][4] = {};

  // Chunk slot d = i*256 + tid holds tile chunk (row = d>>3, col = (d&7)^(row&7));
  // row&7 == (tid>>3)&7 and d&7 == tid&7 for all i, so col is loop-invariant.
  const int srow = tid >> 3;                   // 0..31
  const int scol8 = (tid & 7) ^ (srow & 7);    // chunk column 0..7 (swizzled)
  const unsigned short* Bg = Bt + (long)(n0 + srow) * K_DIM + scol8 * 8;
  unsigned short* Bsd = Bs + tid * 8;
  const float* xg = x + (long)(m0 + srow) * K_DIM + scol8 * 8;
  unsigned short* Asd = As + tid * 8;

  for (int k0 = 0; k0 < K_DIM; k0 += BK) {
    __syncthreads();  // all waves done reading previous tile
    // B: async DMA (in flight while we do A's cos staging below)
#pragma unroll
    for (int i = 0; i < 4; ++i)
      GLD_LDS(Bg + (long)i * 32 * K_DIM, Bsd + i * 2048);
    Bg += BK;

    // A: fp32 load + theta + cos + bf16 pack + LDS write (same swizzled slots)
    const int kc = k0 + scol8 * 8;             // global k of this thread's chunk
    const float4 t0 = *(const float4*)(theta + kc);
    const float4 t1 = *(const float4*)(theta + kc + 4);
#pragma unroll
    for (int i = 0; i < 4; ++i) {
      const float* xp = xg + (long)i * 32 * K_DIM + k0;
      const float4 x0 = *(const float4*)(xp);
      const float4 x1 = *(const float4*)(xp + 4);
      union { unsigned short s[8]; short8 v; } o;
      o.s[0] = f2bf(__cosf(x0.x + t0.x));
      o.s[1] = f2bf(__cosf(x0.y + t0.y));
      o.s[2] = f2bf(__cosf(x0.z + t0.z));
      o.s[3] = f2bf(__cosf(x0.w + t0.w));
      o.s[4] = f2bf(__cosf(x1.x + t1.x));
      o.s[5] = f2bf(__cosf(x1.y + t1.y));
      o.s[6] = f2bf(__cosf(x1.z + t1.z));
      o.s[7] = f2bf(__cosf(x1.w + t1.w));
      *(short8*)(Asd + i * 2048) = o.v;
    }
    __syncthreads();  // drains vmcnt (B DMA) + lgkmcnt (A writes)

#pragma unroll
    for (int s = 0; s < 2; ++s) {
      const int kr = s * 32 + (lane >> 4) * 8;
      const int c = kr >> 3;  // chunk column 0..7
      short8 af[4], bf[4];
#pragma unroll
      for (int i = 0; i < 4; ++i) {
        const int r = wm + i * 16 + (lane & 15);
        af[i] = *(const short8*)(As + r * BK + ((c ^ (r & 7)) * 8));
      }
#pragma unroll
      for (int j = 0; j < 4; ++j) {
        const int r = wn + j * 16 + (lane & 15);
        bf[j] = *(const short8*)(Bs + r * BK + ((c ^ (r & 7)) * 8));
      }
#pragma unroll
      for (int i = 0; i < 4; ++i)
#pragma unroll
        for (int j = 0; j < 4; ++j)
          acc[i][j] = __builtin_amdgcn_mfma_f32_16x16x32_bf16(af[i], bf[j], acc[i][j], 0, 0, 0);
    }
  }

  // Epilogue: D[row=(lane>>4)*4+r][col=lane&15] per 16x16 frag (m89-verified layout).
  const int cn = lane & 15;
  const int rq = (lane >> 4) * 4;
#pragma unroll
  for (int j = 0; j < 4; ++j) {
    const int n = n0 + wn + j * 16 + cn;
    const float bv = bias[n];
#pragma unroll
    for (int i = 0; i < 4; ++i) {
      const long mb = (long)(m0 + wm + i * 16 + rq) * N_DIM + n;
#pragma unroll
      for (int r = 0; r < 4; ++r)
        C[mb + (long)r * N_DIM] = acc[i][j][r] + bv;
    }
  }
}

extern "C" void kernel_launch(void* const* d_in, const int* in_sizes, int n_in,
                              void* d_out, int out_size, void* d_ws, size_t ws_size,
                              hipStream_t stream) {
  const float* x = (const float*)d_in[0];      // [8,2048,1024]
  const float* theta = (const float*)d_in[1];  // [128,8] -> flat 1024
  const float* W = (const float*)d_in[2];      // [1024,1024]
  const float* b = (const float*)d_in[3];      // [1024]
  float* out = (float*)d_out;                  // [8,2048,1024] f32

  unsigned short* Wbf = (unsigned short*)d_ws;  // 2 MB

  hipLaunchKernelGGL(prep_w, dim3(PREP_W_BLOCKS), dim3(256), 0, stream, W, Wbf);
  hipLaunchKernelGGL(gemm_fused, dim3(N_DIM / 128, M_DIM / 128), dim3(256), 0, stream,
                     x, theta, Wbf, b, out);
}

// Round 6
// 169.395 us; speedup vs baseline: 1.1370x; 1.1370x over previous
//
#include <hip/hip_runtime.h>
#include <hip/hip_bf16.h>
#include <stdint.h>

// Problem constants (B=8, S=2048, E=1024, H=128, DK=8)
#define M_DIM 16384   // B*S
#define N_DIM 1024    // E (output features)
#define K_DIM 1024    // E (reduction)

typedef __attribute__((ext_vector_type(8))) short short8;
typedef __attribute__((ext_vector_type(4))) float f32x4;

// async global->LDS, 16B per lane. LDS dest must be wave-uniform base + lane*16.
#define GLD_LDS(g, l) __builtin_amdgcn_global_load_lds( \
    (const __attribute__((address_space(1))) unsigned int*)(g), \
    (__attribute__((address_space(3))) unsigned int*)(l), 16, 0, 0)

__device__ __forceinline__ unsigned short f2bf(float f) {
  union { float f; unsigned int u; } v;
  v.f = f;
  unsigned int u = v.u + 0x7FFFu + ((v.u >> 16) & 1u);  // RNE
  return (unsigned short)(u >> 16);
}

// Fused prep, lane-contiguous (r4-measured): block owns 2048 contiguous elems.
// Blocks [0,8192): A = bf16(cos(x+theta)); [8192,8704): W cast. cos computed 1x
// per element here (r5 post-mortem: fused-in-GEMM cos = x8 on quarter-rate pipe).
#define PREP_A_BLOCKS (M_DIM * K_DIM / 2048)   // 8192
#define PREP_W_BLOCKS (N_DIM * K_DIM / 2048)   // 512
__global__ __launch_bounds__(256) void prep_all(const float* __restrict__ x,
                                                const float* __restrict__ theta,
                                                const float* __restrict__ W,
                                                unsigned short* __restrict__ A,
                                                unsigned short* __restrict__ Wb) {
  const int tid = threadIdx.x;
  if (blockIdx.x < PREP_A_BLOCKS) {
    const long base = (long)blockIdx.x * 2048;
    const float4 t = *(const float4*)(theta + tid * 4);
#pragma unroll
    for (int p = 0; p < 2; ++p) {
      const long i = base + p * 1024 + tid * 4;
      const float4 xv = *(const float4*)(x + i);
      ushort4 o;
      o.x = f2bf(__cosf(xv.x + t.x));
      o.y = f2bf(__cosf(xv.y + t.y));
      o.z = f2bf(__cosf(xv.z + t.z));
      o.w = f2bf(__cosf(xv.w + t.w));
      *(ushort4*)(A + i) = o;
    }
  } else {
    const long base = (long)(blockIdx.x - PREP_A_BLOCKS) * 2048;
#pragma unroll
    for (int p = 0; p < 2; ++p) {
      const long i = base + p * 1024 + tid * 4;
      const float4 wv = *(const float4*)(W + i);
      ushort4 o;
      o.x = f2bf(wv.x);
      o.y = f2bf(wv.y);
      o.z = f2bf(wv.z);
      o.w = f2bf(wv.w);
      *(ushort4*)(Wb + i) = o;
    }
  }
}

// C[m,n] = sum_k A[m,k]*Bt[n,k] + bias[n].  A:[M,K] bf16, Bt:[N,K] bf16, C:[M,N] f32.
// 128x128 tile, 4 waves of 64x64, 16x16x32 bf16 MFMA, XCD-banded remap (r3).
// NEW (r6): double-buffered LDS with BK=32 half-stages at the SAME 32 KB total
// (no occupancy loss) and SAME barrier count (32) — each barrier's vmcnt(0)
// drain now waits on DMA issued one full compute stage earlier (latency hidden
// intra-wave; r3's single buffer exposed full DMA latency at every barrier).
// BK=32 row = 64 B, so swizzle is col' = c ^ ((r>>1)&3): full-wave read =
// 8 lanes per 16B-bank-group, balanced -> conflict-free (r2-verified criterion).
__global__ __launch_bounds__(256) void gemm_bt(const unsigned short* __restrict__ A,
                                               const unsigned short* __restrict__ Bt,
                                               const float* __restrict__ bias,
                                               float* __restrict__ C) {
  constexpr int BM = 128, BK = 32;
  __shared__ unsigned short As[2 * BM * BK];  // 2 x 8 KB
  __shared__ unsigned short Bs[2 * BM * BK];  // 2 x 8 KB
  const int tid = threadIdx.x;

  const int L = blockIdx.y * 8 + blockIdx.x;  // linear dispatch id
  const int bx = (L >> 3) & 7;                // N-tile 0..7
  const int by = (L & 7) * 16 + (L >> 6);     // M-tile 0..127, banded per XCD
  const int m0 = by * BM;
  const int n0 = bx * BM;

  const int lane = tid & 63;
  const int wave = tid >> 6;
  const int wm = (wave >> 1) * 64;  // wave tile origin in M
  const int wn = (wave & 1) * 64;   // wave tile origin in N

  f32x4 acc[4][4] = {};

  // DMA slot d = i*256 + tid -> (row = i*64 + tid>>2, col' = tid&3); stored
  // global chunk col g = col' ^ ((row>>1)&3) = (tid&3) ^ ((tid>>3)&3),
  // i-independent. Dest = wave-uniform + lane*16 (DMA constraint) holds.
  const int srow = tid >> 2;                              // 0..63
  const int scol = ((tid & 3) ^ ((tid >> 3) & 3)) * 8;    // swizzled source col
  const unsigned short* Ag = A + (long)(m0 + srow) * K_DIM + scol;
  const unsigned short* Bg = Bt + (long)(n0 + srow) * K_DIM + scol;
  unsigned short* Asd = As + tid * 8;
  unsigned short* Bsd = Bs + tid * 8;

#define STAGE(buf, koff) \
  do { \
    GLD_LDS(Ag + (koff), Asd + (buf) * 4096); \
    GLD_LDS(Ag + (koff) + 64 * K_DIM, Asd + (buf) * 4096 + 2048); \
    GLD_LDS(Bg + (koff), Bsd + (buf) * 4096); \
    GLD_LDS(Bg + (koff) + 64 * K_DIM, Bsd + (buf) * 4096 + 2048); \
  } while (0)

  const int c = lane >> 4;   // k-chunk col 0..3 (covers k 0..31 with kh=c*8)
  const int fr = lane & 15;

#define COMPUTE(buf) \
  do { \
    const unsigned short* Ab = As + (buf) * 4096; \
    const unsigned short* Bb = Bs + (buf) * 4096; \
    short8 af[4], bf[4]; \
    _Pragma("unroll") \
    for (int i = 0; i < 4; ++i) { \
      const int r = wm + i * 16 + fr; \
      af[i] = *(const short8*)(Ab + r * BK + ((c ^ ((r >> 1) & 3)) * 8)); \
    } \
    _Pragma("unroll") \
    for (int j = 0; j < 4; ++j) { \
      const int r = wn + j * 16 + fr; \
      bf[j] = *(const short8*)(Bb + r * BK + ((c ^ ((r >> 1) & 3)) * 8)); \
    } \
    _Pragma("unroll") \
    for (int i = 0; i < 4; ++i) \
      _Pragma("unroll") \
      for (int j = 0; j < 4; ++j) \
        acc[i][j] = __builtin_amdgcn_mfma_f32_16x16x32_bf16(af[i], bf[j], acc[i][j], 0, 0, 0); \
  } while (0)

  // Prologue: stage 0 -> buf0.
  STAGE(0, 0);

#pragma unroll 2
  for (int it = 0; it < 16; ++it) {
    const int k2 = it * 2 * BK;  // stage 2*it k-offset
    __syncthreads();             // drains DMA for buf0 (+ prev buf1 reads)
    STAGE(1, k2 + BK);           // prefetch stage 2*it+1 -> buf1 (always valid)
    COMPUTE(0);                  // stage 2*it
    __syncthreads();             // drains buf1 DMA (+ buf0 reads just issued)
    if (it < 15)
      STAGE(0, k2 + 2 * BK);     // prefetch stage 2*it+2 -> buf0
    COMPUTE(1);                  // stage 2*it+1
  }

  // Epilogue: D[row=(lane>>4)*4+r][col=lane&15] per 16x16 frag (m89-verified layout).
  const int cn = lane & 15;
  const int rq = (lane >> 4) * 4;
#pragma unroll
  for (int j = 0; j < 4; ++j) {
    const int n = n0 + wn + j * 16 + cn;
    const float bv = bias[n];
#pragma unroll
    for (int i = 0; i < 4; ++i) {
      const long mb = (long)(m0 + wm + i * 16 + rq) * N_DIM + n;
#pragma unroll
      for (int r = 0; r < 4; ++r)
        C[mb + (long)r * N_DIM] = acc[i][j][r] + bv;
    }
  }
#undef STAGE
#undef COMPUTE
}

extern "C" void kernel_launch(void* const* d_in, const int* in_sizes, int n_in,
                              void* d_out, int out_size, void* d_ws, size_t ws_size,
                              hipStream_t stream) {
  const float* x = (const float*)d_in[0];      // [8,2048,1024]
  const float* theta = (const float*)d_in[1];  // [128,8] -> flat 1024
  const float* W = (const float*)d_in[2];      // [1024,1024]
  const float* b = (const float*)d_in[3];      // [1024]
  float* out = (float*)d_out;                  // [8,2048,1024] f32

  unsigned short* Abf = (unsigned short*)d_ws;                   // 33.5 MB
  unsigned short* Wbf = Abf + (size_t)M_DIM * K_DIM;             // +2 MB

  hipLaunchKernelGGL(prep_all, dim3(PREP_A_BLOCKS + PREP_W_BLOCKS), dim3(256), 0,
                     stream, x, theta, W, Abf, Wbf);
  hipLaunchKernelGGL(gemm_bt, dim3(N_DIM / 128, M_DIM / 128), dim3(256), 0, stream,
                     Abf, Wbf, b, out);
}